// Round 8
// baseline (33.222 us; speedup 1.0000x reference)
//
#include <hip/hip_runtime.h>
#include <math.h>

// RoI max pooling: feats (1,256,128,128) f32, rois (1,256,4) int32 {x,y,w,h},
// out (N=256, C=256, 7, 7) f32.  One wave per (n, c).
//
// Lane map (load phase): q = lane&7 (column quad), b = lane>>3 (row bin).
// STRAIGHT-LINE loads: every lane always issues 8 row loads per quad slot
// (dup-row clamp r = min(dr, nr-1) folded into the address; operand multiset
// identical to the reference's masked dr in range(MAX_BIN=8); dup rows are
// L1 hits). No branches in the load phase -> compiler batches ALL loads into
// one in-flight group (VGPR ~80), ONE latency exposure instead of 3-4
// serialized L2 round trips (this was the R6 limiter: VGPR_Count=12 proved
// loads were serialized by the per-iteration uniform branches).
// Stores are UNMASKED: lanes with b==7 write bin-6 duplicates, masked-q
// lanes write quad-0 duplicates -- value-identical to the legitimate writer
// at the same address, so no divergence needed.
// Two quad slots cover cols [0,64): slot1 = 4q, slot2 = 32+4q; slot2 is
// skipped by ONE wave-uniform branch when wa<=32 (~50% of rois).
//
// Read phase: lane l=i*7+j IS the output offset; reads lds[i][pad+sxr..+7],
// masks t<wj (MAX_BIN clamp), 7 maxes, one contiguous 196B store.
// Same-wave DS ordering is in-order -> lgkmcnt(0) fence, no barrier.

constexpr int kC = 256, kH = 128, kW = 128, kN = 256, kOut = 7;
constexpr int kStr = 68;  // dwords/bin-row: 16B-aligned

__device__ __forceinline__ float4 fmax4(float4 a, const float4 b) {
  a.x = fmaxf(a.x, b.x); a.y = fmaxf(a.y, b.y);
  a.z = fmaxf(a.z, b.z); a.w = fmaxf(a.w, b.w);
  return a;
}

template <bool Q2>
__device__ __forceinline__ void load_phase(
    const float* __restrict__ prow, const int nrm1,
    const int c1, const int c2, const int bin, float* __restrict__ wl) {
  float4 v1[8], v2[8];
#pragma unroll
  for (int dr = 0; dr < 8; ++dr) {
    const int rofs = ((dr <= nrm1) ? dr : nrm1) << 7;  // dup-row clamp
    v1[dr] = *(const float4*)(prow + rofs + c1);
    if (Q2) v2[dr] = *(const float4*)(prow + rofs + c2);
  }
  float4 m1 = fmax4(fmax4(fmax4(v1[0], v1[1]), fmax4(v1[2], v1[3])),
                    fmax4(fmax4(v1[4], v1[5]), fmax4(v1[6], v1[7])));
  *(float4*)(wl + bin * kStr + c1) = m1;
  if (Q2) {
    float4 m2 = fmax4(fmax4(fmax4(v2[0], v2[1]), fmax4(v2[2], v2[3])),
                      fmax4(fmax4(v2[4], v2[5]), fmax4(v2[6], v2[7])));
    *(float4*)(wl + bin * kStr + c2) = m2;
  }
}

__global__ __launch_bounds__(256, 4) void roipool_kernel(
    const float* __restrict__ feats,
    const int* __restrict__ rois,
    float* __restrict__ out) {
  __shared__ float lds[4][7 * kStr];  // 7616 B

  const int lane = threadIdx.x & 63;
  const int wid  = __builtin_amdgcn_readfirstlane(threadIdx.x) >> 6;
  const int bid  = blockIdx.x;

  // XCD-affine mapping (perf heuristic): xcd = bid & 7, n-fastest per cg
  const int xcd = bid & 7;
  const int idx = bid >> 3;
  const int n   = idx & (kN - 1);
  const int cg  = ((idx >> 8) << 3) | xcd;
  const int c   = (cg << 2) | wid;

  const int4 roi = ((const int4*)rois)[n];   // n block-uniform -> s_load
  const int x = __builtin_amdgcn_readfirstlane(roi.x);
  const int y = __builtin_amdgcn_readfirstlane(roi.y);
  const int w = __builtin_amdgcn_readfirstlane(roi.z);
  const int h = __builtin_amdgcn_readfirstlane(roi.w);

  const int xa  = x & ~3;
  const int pad = x - xa;
  const int wa  = pad + w;          // <= 59

  const int q  = lane & 7;          // column-quad slot
  const int b  = lane >> 3;         // row-bin slot; b==7 duplicates bin 6
  const int bc = (b < 7) ? b : 6;

  // per-lane bin row bounds (magic-div by 7)
  const int bh   = bc * h;
  const int s_b  = bh / 7;
  int nr         = (bh + h + 6) / 7 - s_b;
  if (nr > 8) nr = 8;               // MAX_BIN clamp
  const int nrm1 = nr - 1;
  const int sy_b = y + s_b;

  const int c1r = 4 * q;
  const int c2r = 32 + 4 * q;
  // masked slots load col 0 -> value-identical duplicate of the q=0 writer
  const int c1 = (c1r < wa) ? c1r : 0;
  const int c2 = (c2r < wa) ? c2r : 0;

  const float* __restrict__ prow =
      feats + (((unsigned)c << 14) + ((unsigned)sy_b << 7) + (unsigned)xa);

  float* __restrict__ wl = lds[wid];
  if (wa > 32) load_phase<true >(prow, nrm1, c1, c2, bc, wl);
  else         load_phase<false>(prow, nrm1, c1, c2, bc, wl);

  // drain LDS writes before cross-lane reads (same-wave, no barrier)
  asm volatile("s_waitcnt lgkmcnt(0)" ::: "memory");

  // read phase: lane l = i*7 + j -> output offset directly
  const int l49 = (lane < 49) ? lane : 48;
  const int i   = (l49 * 37) >> 8;                 // floor(l49/7)
  const int j   = l49 - i * 7;
  const int jw  = j * w;
  const int sxr = (jw * 9363) >> 16;               // floor(jw/7)
  const int exr = ((jw + w + 6) * 9363) >> 16;     // floor(((j+1)w+6)/7)
  int wj = exr - sxr;
  if (wj > 8) wj = 8;                              // MAX_BIN clamp

  const float* __restrict__ rbase = wl + i * kStr + pad + sxr;
  float acc = rbase[0];                            // t=0 always valid
#pragma unroll
  for (int t = 1; t < 8; ++t) {
    const float v = rbase[t];
    acc = fmaxf(acc, (t < wj) ? v : -INFINITY);    // cndmask discards junk
  }

  if (lane < 49)
    out[((size_t)n * kC + c) * 49 + lane] = acc;
}

extern "C" void kernel_launch(void* const* d_in, const int* in_sizes, int n_in,
                              void* d_out, int out_size, void* d_ws, size_t ws_size,
                              hipStream_t stream) {
  const float* feats = (const float*)d_in[0];
  const int*   rois  = (const int*)d_in[1];
  float*       out   = (float*)d_out;
  dim3 grid((kC / 4) * kN);
  dim3 block(256);
  roipool_kernel<<<grid, block, 0, stream>>>(feats, rois, out);
}

// Round 9
// 27.521 us; speedup vs baseline: 1.2071x; 1.2071x over previous
//
#include <hip/hip_runtime.h>
#include <math.h>

// RoI max pooling: feats (1,256,128,128) f32, rois (1,256,4) int32 {x,y,w,h},
// out (N=256, C=256, 7, 7) f32.  One wave per (n, c).
//
// Lane map (load phase): q = lane&7 (column quad), b = lane>>3 (row bin,
// b==7 fully masked). Per bin, 8 row loads into v[8] (init -INF), each
// EXEC-MASKED by (b<7) && (quad < wa) && (dr < nr_b): masked lanes issue
// no L1 requests -> bytes through L1 drop from ~9.3KB to ~5KB per wave
// (R8 proved dur tracks L1 delivery bytes, not load batching).
// dr is a literal -> all 8 loads share one base reg with offset:dr*512
// immediates (no per-load addressing VALU). Loads batch (no data deps),
// one waitcnt, then an unconditional fmax tree; stores masked (m1/m2).
// Two quad slots cover cols [0,64): slot1 = 4q, slot2 = 32+4q; slot2
// skipped wave-uniformly when wa<=32; rows skipped uniformly at dr>=nrb
// (nrb = min(8,(h+12)/7) >= every bin's nr).
// All addresses in-plane even when masked: sy_b+7 <= 127, 16B-aligned
// quads never cross a row (start col <= 127 -> quad within row).
//
// Read phase: lane l=i*7+j IS the output offset; reads lds[i][pad+sxr..+7],
// masks t<wj (MAX_BIN clamp; valid t stay within written quads), 7 maxes,
// one contiguous 196B store. Same-wave DS in-order -> lgkmcnt(0), no barrier.

constexpr int kC = 256, kH = 128, kW = 128, kN = 256, kOut = 7;
constexpr int kStr = 68;  // dwords/bin-row: 16B-aligned, chunk spread 17*bin mod 8

__device__ __forceinline__ float4 fmax4(float4 a, const float4 b) {
  a.x = fmaxf(a.x, b.x); a.y = fmaxf(a.y, b.y);
  a.z = fmaxf(a.z, b.z); a.w = fmaxf(a.w, b.w);
  return a;
}

template <bool Q2>
__device__ __forceinline__ void load_phase(
    const float* __restrict__ prow, const int nr, const int nrb,
    const int c1, const int c2, const bool m1, const bool m2,
    const int bin, float* __restrict__ wl) {
  const float4 kNeg = make_float4(-INFINITY, -INFINITY, -INFINITY, -INFINITY);
  float4 v1[8], v2[8];
#pragma unroll
  for (int dr = 0; dr < 8; ++dr) {
    v1[dr] = kNeg;
    if (Q2) v2[dr] = kNeg;
    if (dr < nrb) {                        // wave-uniform row skip
      if (m1 && dr < nr) v1[dr] = *(const float4*)(prow + dr * kW + c1);
      if (Q2) {
        if (m2 && dr < nr) v2[dr] = *(const float4*)(prow + dr * kW + c2);
      }
    }
  }
  float4 r1 = fmax4(fmax4(fmax4(v1[0], v1[1]), fmax4(v1[2], v1[3])),
                    fmax4(fmax4(v1[4], v1[5]), fmax4(v1[6], v1[7])));
  if (m1) *(float4*)(wl + bin * kStr + c1) = r1;
  if (Q2) {
    float4 r2 = fmax4(fmax4(fmax4(v2[0], v2[1]), fmax4(v2[2], v2[3])),
                      fmax4(fmax4(v2[4], v2[5]), fmax4(v2[6], v2[7])));
    if (m2) *(float4*)(wl + bin * kStr + c2) = r2;
  }
}

__global__ __launch_bounds__(256, 4) void roipool_kernel(
    const float* __restrict__ feats,
    const int* __restrict__ rois,
    float* __restrict__ out) {
  __shared__ float lds[4][7 * kStr];  // 7616 B

  const int lane = threadIdx.x & 63;
  const int wid  = __builtin_amdgcn_readfirstlane(threadIdx.x) >> 6;
  const int bid  = blockIdx.x;

  // XCD-affine mapping (perf heuristic): xcd = bid & 7, n-fastest per cg
  const int xcd = bid & 7;
  const int idx = bid >> 3;
  const int n   = idx & (kN - 1);
  const int cg  = ((idx >> 8) << 3) | xcd;
  const int c   = (cg << 2) | wid;

  const int4 roi = ((const int4*)rois)[n];   // n uniform -> scalar load path
  const int x = __builtin_amdgcn_readfirstlane(roi.x);
  const int y = __builtin_amdgcn_readfirstlane(roi.y);
  const int w = __builtin_amdgcn_readfirstlane(roi.z);
  const int h = __builtin_amdgcn_readfirstlane(roi.w);

  const int xa  = x & ~3;
  const int pad = x - xa;
  const int wa  = pad + w;          // <= 59

  const int q  = lane & 7;          // column-quad slot
  const int b  = lane >> 3;         // row-bin slot; b==7 fully masked
  const int bc = (b < 7) ? b : 6;

  // per-lane bin row bounds (magic-div by 7)
  const int bh   = bc * h;
  const int s_b  = bh / 7;
  int nr         = (bh + h + 6) / 7 - s_b;
  if (nr > 8) nr = 8;               // MAX_BIN clamp
  const int sy_b = y + s_b;

  int nrb = (h + 12) / 7;           // uniform: nrb >= every bin's nr
  if (nrb > 8) nrb = 8;

  const int c1 = 4 * q;
  const int c2 = 32 + 4 * q;
  const bool m1 = (b < 7) && (c1 < wa);
  const bool m2 = (b < 7) && (c2 < wa);

  const float* __restrict__ prow =
      feats + (((unsigned)c << 14) + ((unsigned)sy_b << 7) + (unsigned)xa);

  float* __restrict__ wl = lds[wid];
  if (wa > 32) load_phase<true >(prow, nr, nrb, c1, c2, m1, m2, bc, wl);
  else         load_phase<false>(prow, nr, nrb, c1, c2, m1, m2, bc, wl);

  // drain LDS writes before cross-lane reads (same-wave, no barrier)
  asm volatile("s_waitcnt lgkmcnt(0)" ::: "memory");

  // read phase: lane l = i*7 + j -> output offset directly
  const int l49 = (lane < 49) ? lane : 48;
  const int i   = (l49 * 37) >> 8;                 // floor(l49/7)
  const int j   = l49 - i * 7;
  const int jw  = j * w;
  const int sxr = (jw * 9363) >> 16;               // floor(jw/7)
  const int exr = ((jw + w + 6) * 9363) >> 16;     // floor(((j+1)w+6)/7)
  int wj = exr - sxr;
  if (wj > 8) wj = 8;                              // MAX_BIN clamp

  const float* __restrict__ rbase = wl + i * kStr + pad + sxr;
  float acc = rbase[0];                            // t=0 always valid
#pragma unroll
  for (int t = 1; t < 8; ++t) {
    const float v = rbase[t];
    acc = fmaxf(acc, (t < wj) ? v : -INFINITY);    // cndmask discards junk
  }

  if (lane < 49)
    out[((size_t)n * kC + c) * 49 + lane] = acc;
}

extern "C" void kernel_launch(void* const* d_in, const int* in_sizes, int n_in,
                              void* d_out, int out_size, void* d_ws, size_t ws_size,
                              hipStream_t stream) {
  const float* feats = (const float*)d_in[0];
  const int*   rois  = (const int*)d_in[1];
  float*       out   = (float*)d_out;
  dim3 grid((kC / 4) * kN);
  dim3 block(256);
  roipool_kernel<<<grid, block, 0, stream>>>(feats, rois, out);
}